// Round 3
// baseline (135.311 us; speedup 1.0000x reference)
//
#include <hip/hip_runtime.h>
#include <math.h>

#define N_NODES 50000
#define N_EDGES 600000
#define ALPHA 0.01f
#define NB2 512            // e-streaming blocks in KA
#define NB1 1563           // node-GEMM blocks in KA (1563*32 >= 50000)
#define KB_GRID 1024
#define KC_GRID 256

__device__ __forceinline__ float leaky(float x) { return x > 0.f ? x : ALPHA * x; }

// ================= KA: fused [e-stream -> dsc] || [node GEMM -> hp, ps, pd] ==========
// blocks [0, NB2): zero w, compute w_em redundantly, dsc[i] = e[i,:] . w_em
// blocks [NB2, NB2+NB1): 32-row tile of h_prime = leaky(h @ Wu); ps/pd scalars
__global__ __launch_bounds__(256) void ka_fused(
        const float* __restrict__ h, const float* __restrict__ Wu,
        const float* __restrict__ a, const float* __restrict__ e,
        const float* __restrict__ W_e, const float* __restrict__ W_m,
        float* __restrict__ hp, float* __restrict__ ps, float* __restrict__ pd,
        float* __restrict__ w, float* __restrict__ dsc) {
    int t = threadIdx.x;
    if (blockIdx.x < NB2) {
        // ---- edge-stream role ----
        __shared__ float swem[64];
        int gid = blockIdx.x * 256 + t;
        for (int i = gid; i < N_NODES; i += NB2 * 256) w[i] = 0.f;
        if (t < 64) {
            float acc = 0.f;
            const float* row = W_e + t * 128;
            #pragma unroll 8
            for (int k = 0; k < 128; ++k) acc += row[k] * W_m[k];
            swem[t] = acc;
        }
        __syncthreads();
        int lane = t & 63;
        int q = lane & 15;
        int sub = lane >> 4;
        int gw = (blockIdx.x * 256 + t) >> 6;     // global wave id 0..NB2*4-1
        const int nw = NB2 * 4;
        float4 wv = ((const float4*)swem)[q];
        for (int base = gw * 4; base < N_EDGES; base += nw * 4) {
            int eidx = base + sub;                 // base%4==0, E%4==0 -> in range
            float4 ev = ((const float4*)(e + (size_t)eidx * 64))[q];
            float d = ev.x * wv.x + ev.y * wv.y + ev.z * wv.z + ev.w * wv.w;
            d += __shfl_xor(d, 1);
            d += __shfl_xor(d, 2);
            d += __shfl_xor(d, 4);
            d += __shfl_xor(d, 8);
            if (q == 0) dsc[eidx] = d;
        }
    } else {
        // ---- node-GEMM role ----
        __shared__ float sh[32 * 132];
        __shared__ float sa[256];
        if (t < 256) sa[t] = a[t];
        int rl = t >> 5;
        int c4 = t & 31;
        int base = (blockIdx.x - NB2) * 32;

        for (int i = t; i < 32 * 32; i += 256) {
            int row = i >> 5, c = i & 31;
            float4 v = make_float4(0.f, 0.f, 0.f, 0.f);
            if (base + row < N_NODES)
                v = ((const float4*)h)[(size_t)(base + row) * 32 + c];
            *(float4*)(sh + row * 132 + c * 4) = v;
        }
        __syncthreads();

        float acc[4][4];
        #pragma unroll
        for (int j = 0; j < 4; ++j)
            #pragma unroll
            for (int x = 0; x < 4; ++x) acc[j][x] = 0.f;

        #pragma unroll 4
        for (int k = 0; k < 128; ++k) {
            float4 wv = ((const float4*)(Wu + k * 128))[c4];
            #pragma unroll
            for (int j = 0; j < 4; ++j) {
                float hv = sh[(rl + 8 * j) * 132 + k];
                acc[j][0] += hv * wv.x;
                acc[j][1] += hv * wv.y;
                acc[j][2] += hv * wv.z;
                acc[j][3] += hv * wv.w;
            }
        }

        int cb = c4 * 4;
        #pragma unroll
        for (int j = 0; j < 4; ++j) {
            int row = base + rl + 8 * j;
            float4 o;
            o.x = leaky(acc[j][0]);
            o.y = leaky(acc[j][1]);
            o.z = leaky(acc[j][2]);
            o.w = leaky(acc[j][3]);
            float p1 = o.x * sa[cb] + o.y * sa[cb + 1] + o.z * sa[cb + 2] + o.w * sa[cb + 3];
            float p2 = o.x * sa[128 + cb] + o.y * sa[128 + cb + 1] +
                       o.z * sa[128 + cb + 2] + o.w * sa[128 + cb + 3];
            #pragma unroll
            for (int m = 16; m >= 1; m >>= 1) {
                p1 += __shfl_xor(p1, m);
                p2 += __shfl_xor(p2, m);
            }
            if (row < N_NODES) {
                ((float4*)(hp + (size_t)row * 128))[c4] = o;
                if (c4 == 0) { ps[row] = p1; pd[row] = p2; }
            }
        }
    }
}

// ================= KB: per-edge p = exp(sigmoid(ps+pd)*dsc); w[src]+=p; Spart =========
__global__ __launch_bounds__(256) void kb_edge(
        const int* __restrict__ src, const int* __restrict__ dst,
        const float* __restrict__ dsc, const float* __restrict__ ps,
        const float* __restrict__ pd, float* __restrict__ w,
        double* __restrict__ Spart) {
    int t = threadIdx.x;
    int gid = blockIdx.x * 256 + t;
    double sacc = 0.0;
    for (int i = gid; i < N_EDGES; i += KB_GRID * 256) {
        int s = src[i];
        float score = ps[s] + pd[dst[i]];
        float sig = 1.f / (1.f + expf(-score));
        float p = expf(sig * dsc[i]);
        atomicAdd(&w[s], p);
        sacc += (double)p;
    }
    __shared__ double sred[256];
    sred[t] = sacc;
    __syncthreads();
    for (int s2 = 128; s2 > 0; s2 >>= 1) {
        if (t < s2) sred[t] += sred[t + s2];
        __syncthreads();
    }
    if (t == 0) Spart[blockIdx.x] = sred[0];
}

// ================= KC: hgpart[b][col] = sum_rows w[row]*leaky(hp[row][col]) ===========
__global__ __launch_bounds__(256) void kc_hg(
        const float* __restrict__ hp, const float* __restrict__ w,
        double* __restrict__ hgpart) {
    int t = threadIdx.x;
    int col = t & 127;
    int half = t >> 7;
    double acc = 0.0;
    for (int r0 = blockIdx.x * 2; r0 < N_NODES; r0 += KC_GRID * 2) {
        int row = r0 + half;                       // N even
        float wvv = w[row];
        float g = leaky(hp[(size_t)row * 128 + col]);
        acc += (double)(wvv * g);
    }
    __shared__ double sred[256];
    sred[t] = acc;
    __syncthreads();
    if (t < 128) hgpart[blockIdx.x * 128 + t] = sred[t] + sred[t + 128];
}

// ================= KD: reduce S/hg + full MLP in one block ============================
__global__ __launch_bounds__(1024) void kd_tail(
        const double* __restrict__ Spart, const double* __restrict__ hgpart,
        const float* __restrict__ W1, const float* __restrict__ b1,
        const float* __restrict__ W2, const float* __restrict__ b2,
        const float* __restrict__ W3, const float* __restrict__ b3,
        const float* __restrict__ W4, const float* __restrict__ b4,
        float* __restrict__ out) {
    __shared__ double dred[1024];
    __shared__ float fpart[1024];
    __shared__ float hgs[128];
    __shared__ float x1s[512];
    __shared__ float x2s[128];
    __shared__ float x3s[16];
    int t = threadIdx.x;

    // S = sum Spart[0..KB_GRID)
    dred[t] = Spart[t];                            // KB_GRID == 1024
    __syncthreads();
    for (int st = 512; st > 0; st >>= 1) {
        if (t < st) dred[t] += dred[t + st];
        __syncthreads();
    }
    double S = dred[0];
    __syncthreads();

    // hg[c] = (sum_b hgpart[b][c]) / S ; 8 groups x 128 cols, 32 rows each
    {
        int c = t & 127, g = t >> 7;
        double acc = 0.0;
        #pragma unroll 4
        for (int i = 0; i < 32; ++i)
            acc += hgpart[(size_t)(g * 32 + i) * 128 + c];
        dred[t] = acc;
        __syncthreads();
        if (t < 128) {
            double tot = 0.0;
            #pragma unroll
            for (int g2 = 0; g2 < 8; ++g2) tot += dred[t + 128 * g2];
            hgs[t] = (float)(tot / S);
        }
    }
    __syncthreads();

    // L1: x1 = relu(hg @ W1 + b1); 512 outputs x 2 d-groups of 64
    {
        int o = t & 511, g = t >> 9;
        float acc = 0.f;
        #pragma unroll 8
        for (int i = 0; i < 64; ++i) {
            int d = g * 64 + i;
            acc += hgs[d] * W1[d * 512 + o];
        }
        fpart[t] = acc;
        __syncthreads();
        if (t < 512) x1s[t] = fmaxf(fpart[t] + fpart[t + 512] + b1[t], 0.f);
    }
    __syncthreads();

    // L2: x2 = relu(x1 @ W2 + b2); 128 outputs x 8 k-groups of 64
    {
        int o = t & 127, g = t >> 7;
        float acc = 0.f;
        #pragma unroll 8
        for (int i = 0; i < 64; ++i) {
            int k = g * 64 + i;
            acc += x1s[k] * W2[k * 128 + o];
        }
        fpart[t] = acc;
        __syncthreads();
        if (t < 128) {
            float s2 = b2[t];
            #pragma unroll
            for (int g2 = 0; g2 < 8; ++g2) s2 += fpart[t + 128 * g2];
            x2s[t] = fmaxf(s2, 0.f);
        }
    }
    __syncthreads();

    // L3: x3 = relu(x2 @ W3 + b3); 16 outputs x 16 k-groups of 8 (256 threads)
    {
        if (t < 256) {
            int o = t & 15, g = t >> 4;
            float acc = 0.f;
            #pragma unroll
            for (int i = 0; i < 8; ++i) {
                int k = g * 8 + i;
                acc += x2s[k] * W3[k * 16 + o];
            }
            fpart[t] = acc;
        }
        __syncthreads();
        if (t < 16) {
            float s3 = b3[t];
            #pragma unroll
            for (int g2 = 0; g2 < 16; ++g2) s3 += fpart[t + 16 * g2];
            x3s[t] = fmaxf(s3, 0.f);
        }
    }
    __syncthreads();

    if (t == 0) {
        float acc = b4[0];
        #pragma unroll
        for (int k = 0; k < 16; ++k) acc += x3s[k] * W4[k];
        out[0] = acc;
    }
}

extern "C" void kernel_launch(void* const* d_in, const int* in_sizes, int n_in,
                              void* d_out, int out_size, void* d_ws, size_t ws_size,
                              hipStream_t stream) {
    const float* h   = (const float*)d_in[0];
    const float* e   = (const float*)d_in[1];
    const int*   src = (const int*)d_in[2];
    const int*   dst = (const int*)d_in[3];
    const float* W_u = (const float*)d_in[4];
    const float* W_e = (const float*)d_in[5];
    const float* a   = (const float*)d_in[6];
    const float* W_m = (const float*)d_in[7];
    const float* W1  = (const float*)d_in[8];
    const float* b1  = (const float*)d_in[9];
    const float* W2  = (const float*)d_in[10];
    const float* b2  = (const float*)d_in[11];
    const float* W3  = (const float*)d_in[12];
    const float* b3  = (const float*)d_in[13];
    const float* W4  = (const float*)d_in[14];
    const float* b4  = (const float*)d_in[15];
    float* out = (float*)d_out;

    char* ws = (char*)d_ws;
    float*  hp    = (float*)(ws);                     // 50000*128 f = 25,600,000 B
    float*  ps    = (float*)(ws + 25600000);          // 50000 f
    float*  pd    = (float*)(ws + 25800000);          // 50000 f
    float*  w     = (float*)(ws + 26000000);          // 50000 f
    float*  dsc   = (float*)(ws + 26200000);          // 600000 f = 2,400,000 B
    double* Spart = (double*)(ws + 28600000);         // 1024 d
    double* hgpart= (double*)(ws + 28608192);         // 256*128 d -> ends 28,870,336

    hipLaunchKernelGGL(ka_fused, dim3(NB2 + NB1), dim3(256), 0, stream,
                       h, W_u, a, e, W_e, W_m, hp, ps, pd, w, dsc);
    hipLaunchKernelGGL(kb_edge, dim3(KB_GRID), dim3(256), 0, stream,
                       src, dst, dsc, ps, pd, w, Spart);
    hipLaunchKernelGGL(kc_hg, dim3(KC_GRID), dim3(256), 0, stream, hp, w, hgpart);
    hipLaunchKernelGGL(kd_tail, dim3(1), dim3(1024), 0, stream,
                       Spart, hgpart, W1, b1, W2, b2, W3, b3, W4, b4, out);
}